// Round 1
// baseline (4747.778 us; speedup 1.0000x reference)
//
#include <hip/hip_runtime.h>

// LSTM_Actor: T=512 steps, B=2048 rows, D=H=64, 4H=256 gates, A=16 outputs.
// fp32 persistent-block design: 256 blocks x 256 threads, 8 batch rows/block,
// block loops over all 512 timesteps (rows are independent -> no grid sync).
// Wave w (0..3) owns gate quadrant w (PyTorch order i,f,g,o), lane = hidden j.
// Weights staged once in LDS, read once per CU per step (LDS-BW safe).

#define TT 512
#define BB 2048
#define DD 64
#define HH 64
#define AA 16
#define ROWS 8

#if defined(__has_builtin)
#  if __has_builtin(__builtin_amdgcn_exp2f)
#    define EXP2F(x) __builtin_amdgcn_exp2f(x)
#  else
#    define EXP2F(x) exp2f(x)
#  endif
#  if __has_builtin(__builtin_amdgcn_rcpf)
#    define RCPF(x) __builtin_amdgcn_rcpf(x)
#  else
#    define RCPF(x) (1.0f/(x))
#  endif
#else
#  define EXP2F(x) exp2f(x)
#  define RCPF(x) (1.0f/(x))
#endif

__device__ __forceinline__ float sigmoid_f(float x) {
  // 1/(1+e^-x); saturates correctly for large |x| (exp2->0 or inf, rcp(inf)=0)
  return RCPF(1.0f + EXP2F(-1.4426950408889634f * x));
}
__device__ __forceinline__ float tanh_f(float x) {
  // 1 - 2/(1+e^(2x)); correct at +/-inf without NaN
  return 1.0f - 2.0f * RCPF(1.0f + EXP2F(2.8853900817779268f * x));
}

struct SmemT {
  // WTB[kb][g][kk] = Wcat[g][4*kb+kk], Wcat = [W_ih | W_hh] along k (128)
  // per-lane ds_read_b128: lane g stride 16B -> conflict-free
  float WTB[32 * 256 * 4];   // 128 KB
  float xa[ROWS][128];       // [r][k]: k<64 = x_t, k>=64 = h_t ; 4 KB
  float gbuf[ROWS][4][64];   // activated gates [r][q][j], conflict-free r/w ; 8 KB
  float WoT[64][16];         // W_out^T [j][a] ; 4 KB
};                           // total 144 KB < 160 KB -> 1 block/CU

__global__ __launch_bounds__(256, 1)
void lstm_actor_kernel(const float* __restrict__ x,
                       const float* __restrict__ W_ih,
                       const float* __restrict__ W_hh,
                       const float* __restrict__ b_ih,
                       const float* __restrict__ b_hh,
                       const float* __restrict__ W_out,
                       const float* __restrict__ b_out,
                       float* __restrict__ out) {
  __shared__ SmemT s;
  const int tid  = threadIdx.x;
  const int lane = tid & 63;
  const int wv   = tid >> 6;          // wave id == gate quadrant (i,f,g,o)
  const int r0   = blockIdx.x * ROWS; // this block's batch rows

  // ---- stage weights into LDS (one-time; global reads coalesced) ----
  for (int idx = tid; idx < 256 * 64; idx += 256) {
    const int g = idx >> 6, d = idx & 63;
    s.WTB[(d >> 2) * 1024 + g * 4 + (d & 3)]        = W_ih[idx];   // k = d
    s.WTB[(16 + (d >> 2)) * 1024 + g * 4 + (d & 3)] = W_hh[idx];   // k = 64+d
  }
  for (int idx = tid; idx < AA * HH; idx += 256) {
    const int a = idx >> 6, j = idx & 63;
    s.WoT[j][a] = W_out[idx];
  }
  // zero h region
  {
    const int ra = wv * 2;
    s.xa[ra][64 + lane]     = 0.0f;
    s.xa[ra + 1][64 + lane] = 0.0f;
  }
  // load x_0 (8 rows x 64 = 512 contiguous floats; 2 per thread, coalesced)
  {
    const float2 v = *(const float2*)(x + (size_t)r0 * DD + tid * 2);
    const int rr = tid >> 5, dd = (tid & 31) * 2;
    *(float2*)&s.xa[rr][dd] = v;
  }

  const int   gidx   = wv * 64 + lane;          // this thread's gate row
  const float bias_g = b_ih[gidx] + b_hh[gidx]; // fused bias
  const float bo     = b_out[lane & 15];

  float c0 = 0.0f, c1 = 0.0f;  // cell state for rows 2*wv, 2*wv+1 (elementwise role)

  __syncthreads();

  for (int t = 0; t < TT; ++t) {
    // prefetch x_{t+1} into registers; latency hides under the gate GEMV
    float2 xnext;
    if (t + 1 < TT) {
      xnext = *(const float2*)(x + ((size_t)(t + 1) * BB + r0) * DD + tid * 2);
    }

    // ---- gate GEMV: acc[r] = bias + sum_k Wcat[g][k] * xa[r][k] ----
    float acc[ROWS];
#pragma unroll
    for (int r = 0; r < ROWS; ++r) acc[r] = bias_g;

    const float* wb = &s.WTB[gidx * 4];
#pragma unroll 4
    for (int kb = 0; kb < 32; ++kb) {
      const float4 w4 = *(const float4*)(wb + kb * 1024);  // per-lane, conflict-free
#pragma unroll
      for (int r = 0; r < ROWS; ++r) {
        const float4 a4 = *(const float4*)(&s.xa[r][kb * 4]);  // wave-uniform bcast
        acc[r] += w4.x * a4.x + w4.y * a4.y + w4.z * a4.z + w4.w * a4.w;
      }
    }

    // activation for this quadrant (wave-uniform branch, no divergence)
    if (wv == 2) {
#pragma unroll
      for (int r = 0; r < ROWS; ++r) s.gbuf[r][2][lane] = tanh_f(acc[r]);
    } else {
#pragma unroll
      for (int r = 0; r < ROWS; ++r) s.gbuf[r][wv][lane] = sigmoid_f(acc[r]);
    }

    __syncthreads();

    // ---- elementwise c/h update: thread = (hidden j=lane, rows 2wv, 2wv+1) ----
    {
      const int ra = wv * 2, rb = ra + 1;
      float iv = s.gbuf[ra][0][lane], fv = s.gbuf[ra][1][lane],
            gv = s.gbuf[ra][2][lane], ov = s.gbuf[ra][3][lane];
      c0 = fv * c0 + iv * gv;
      const float ha = ov * tanh_f(c0);
      iv = s.gbuf[rb][0][lane]; fv = s.gbuf[rb][1][lane];
      gv = s.gbuf[rb][2][lane]; ov = s.gbuf[rb][3][lane];
      c1 = fv * c1 + iv * gv;
      const float hb = ov * tanh_f(c1);
      s.xa[ra][64 + lane] = ha;   // new h into xa (conflict-free)
      s.xa[rb][64 + lane] = hb;
    }
    // store prefetched x_{t+1} (x_t no longer needed)
    if (t + 1 < TT) {
      const int rr = tid >> 5, dd = (tid & 31) * 2;
      *(float2*)&s.xa[rr][dd] = xnext;
    }
    __syncthreads();

    // ---- output projection: out[t][r][a] = b_out[a] + sum_j h[r][j]*W_out[a][j]
    {
      const int r    = wv * 2 + (lane >> 5);
      const int half = (lane >> 4) & 1;   // j-range split, combined via shfl
      const int a    = lane & 15;
      float sum = 0.0f;
      const float* hrow = &s.xa[r][64 + half * 32];
#pragma unroll
      for (int jj = 0; jj < 32; ++jj)
        sum += hrow[jj] * s.WoT[half * 32 + jj][a];
      sum += __shfl_xor(sum, 16, 64);
      if ((lane & 16) == 0)
        out[((size_t)t * BB + r0 + r) * AA + a] = sum + bo;
    }
  }
}

extern "C" void kernel_launch(void* const* d_in, const int* in_sizes, int n_in,
                              void* d_out, int out_size, void* d_ws, size_t ws_size,
                              hipStream_t stream) {
  const float* x     = (const float*)d_in[0];
  const float* W_ih  = (const float*)d_in[1];
  const float* W_hh  = (const float*)d_in[2];
  const float* b_ih  = (const float*)d_in[3];
  const float* b_hh  = (const float*)d_in[4];
  const float* W_out = (const float*)d_in[5];
  const float* b_out = (const float*)d_in[6];
  float* out = (float*)d_out;

  lstm_actor_kernel<<<dim3(BB / ROWS), dim3(256), 0, stream>>>(
      x, W_ih, W_hh, b_ih, b_hh, W_out, b_out, out);
}

// Round 2
// 496.494 us; speedup vs baseline: 9.5626x; 9.5626x over previous
//
#include <hip/hip_runtime.h>

// LSTM_Actor via bf16 MFMA with hi/lo split (fp32-equivalent accuracy).
// T=512 steps, B=2048 rows, D=H=64, 4H=256 gates, A=16.
// 256 blocks x 512 threads (8 waves), 8 batch rows per block, persistent over t.
// Wave w owns gates [32w, 32w+32) = 2 MFMA n-tiles; recurrent weights live in
// registers as B-fragments (hi+lo): zero weight LDS traffic per step.
// Activations [x_t | h_t] staged in LDS as bf16 hi/lo, padded rows (272B) for
// 2-way-free bank access on ds_read_b128 fragment loads.
// Projection (A=16) fused as 6 MFMAs on wave 0, shifted one step late so the
// main loop needs only 2 barriers.

#define TT 512
#define BB 2048
#define DD 64
#define HH 64
#define AA 16
#define ROWS 8

typedef short bf16x8 __attribute__((ext_vector_type(8)));
typedef float f32x4 __attribute__((ext_vector_type(4)));

#define MFMA16(a, b, c) __builtin_amdgcn_mfma_f32_16x16x32_bf16((a), (b), (c), 0, 0, 0)

#if defined(__has_builtin)
#  if __has_builtin(__builtin_amdgcn_exp2f)
#    define EXP2F(x) __builtin_amdgcn_exp2f(x)
#  else
#    define EXP2F(x) exp2f(x)
#  endif
#  if __has_builtin(__builtin_amdgcn_rcpf)
#    define RCPF(x) __builtin_amdgcn_rcpf(x)
#  else
#    define RCPF(x) (1.0f/(x))
#  endif
#else
#  define EXP2F(x) exp2f(x)
#  define RCPF(x) (1.0f/(x))
#endif

__device__ __forceinline__ float sigmoid_f(float x) {
  return RCPF(1.0f + EXP2F(-1.4426950408889634f * x));
}
__device__ __forceinline__ float tanh_f(float x) {
  return 1.0f - 2.0f * RCPF(1.0f + EXP2F(2.8853900817779268f * x));
}

__device__ __forceinline__ short f2bf(float f) {  // RNE fp32->bf16
  union { float f; unsigned u; } v; v.f = f;
  unsigned r = v.u + 0x7FFFu + ((v.u >> 16) & 1u);
  return (short)(r >> 16);
}
__device__ __forceinline__ float bf2f(short s) {
  union { unsigned u; float f; } v; v.u = ((unsigned)(unsigned short)s) << 16;
  return v.f;
}

struct Smem {
  __align__(16) unsigned short ahi[16][136];  // [row][k] k<64=x_t, k>=64=h_t (hi bf16)
  __align__(16) unsigned short alo[16][136];  // lo residual bf16; 136 pad -> 272B rows
  float gbuf[8][4][64];                       // activated gates [row][quadrant][j]
};                                            // ~16.9 KB

__global__ __launch_bounds__(512, 2)
void lstm_actor_mfma(const float* __restrict__ x,
                     const float* __restrict__ W_ih,
                     const float* __restrict__ W_hh,
                     const float* __restrict__ b_ih,
                     const float* __restrict__ b_hh,
                     const float* __restrict__ W_out,
                     const float* __restrict__ b_out,
                     float* __restrict__ out) {
  __shared__ Smem s;
  const int tid  = threadIdx.x;
  const int lane = tid & 63;
  const int w    = tid >> 6;        // wave id 0..7; also elementwise row
  const int lr   = lane & 15;       // MFMA "16" index
  const int lg   = lane >> 4;       // MFMA k-group 0..3
  const int r0   = blockIdx.x * ROWS;

  // ---- recurrent weight B-fragments in registers (hi/lo split) ----
  // B[k][gate]: lane holds col = lr (gate = nt*16+lr), k = kt*32 + lg*8 + j
  bf16x8 bh[2][4], bl[2][4];
#pragma unroll
  for (int nn = 0; nn < 2; ++nn) {
    const int g = (w * 2 + nn) * 16 + lr;
#pragma unroll
    for (int kt = 0; kt < 4; ++kt) {
      const int k0 = kt * 32 + lg * 8;
      const float* src = (kt < 2) ? (W_ih + g * 64 + k0) : (W_hh + g * 64 + (k0 - 64));
      bf16x8 vh, vl;
#pragma unroll
      for (int j = 0; j < 8; ++j) {
        const float f = src[j];
        const short hi = f2bf(f);
        vh[j] = hi;
        vl[j] = f2bf(f - bf2f(hi));
      }
      bh[nn][kt] = vh; bl[nn][kt] = vl;
    }
  }
  const float bias0 = b_ih[w * 32 + lr]      + b_hh[w * 32 + lr];
  const float bias1 = b_ih[w * 32 + 16 + lr] + b_hh[w * 32 + 16 + lr];

  // ---- projection weights (wave 0 only): B[k=j][col=a] ----
  bf16x8 pbh[2], pbl[2];
  float bo = 0.0f;
  if (w == 0) {
    bo = b_out[lr];
#pragma unroll
    for (int kt = 0; kt < 2; ++kt) {
      const float* src = W_out + lr * 64 + kt * 32 + lg * 8;
      bf16x8 vh, vl;
#pragma unroll
      for (int j = 0; j < 8; ++j) {
        const float f = src[j];
        const short hi = f2bf(f);
        vh[j] = hi;
        vl[j] = f2bf(f - bf2f(hi));
      }
      pbh[kt] = vh; pbl[kt] = vl;
    }
  }

  // ---- init LDS: zero act (incl. pad rows 8..15), then stage x_0 ----
  for (int idx = tid; idx < 16 * 136; idx += 512) {
    ((unsigned short*)s.ahi)[idx] = 0;
    ((unsigned short*)s.alo)[idx] = 0;
  }
  __syncthreads();
  {
    const float x0 = x[(size_t)(r0 + w) * DD + lane];
    const short hi = f2bf(x0);
    s.ahi[w][lane] = (unsigned short)hi;
    s.alo[w][lane] = (unsigned short)f2bf(x0 - bf2f(hi));
  }
  __syncthreads();

  const char* ahi_base = (const char*)&s.ahi[lr][0];  // A row = lr
  const char* alo_base = (const char*)&s.alo[lr][0];

  float c_state = 0.0f;

  for (int t = 0; t < TT; ++t) {
    // prefetch x_{t+1}
    float xn = 0.0f;
    if (t + 1 < TT) xn = x[((size_t)(t + 1) * BB + r0 + w) * DD + lane];

    // ---- A-fragment loads: act [16 x 128] hi/lo ----
    bf16x8 ah[4], al[4];
#pragma unroll
    for (int kt = 0; kt < 4; ++kt) {
      ah[kt] = *(const bf16x8*)(ahi_base + kt * 64 + lg * 16);
      al[kt] = *(const bf16x8*)(alo_base + kt * 64 + lg * 16);
    }

    // ---- gate GEMM: (Ah+Al)(Bh+Bl) ~ AhBh + AlBh + AhBl ----
    f32x4 acc0 = {bias0, bias0, bias0, bias0};
    f32x4 acc1 = {bias1, bias1, bias1, bias1};
#pragma unroll
    for (int kt = 0; kt < 4; ++kt) {
      acc0 = MFMA16(ah[kt], bh[0][kt], acc0);
      acc1 = MFMA16(ah[kt], bh[1][kt], acc1);
    }
#pragma unroll
    for (int kt = 0; kt < 4; ++kt) {
      acc0 = MFMA16(al[kt], bh[0][kt], acc0);
      acc1 = MFMA16(al[kt], bh[1][kt], acc1);
      acc0 = MFMA16(ah[kt], bl[0][kt], acc0);
      acc1 = MFMA16(ah[kt], bl[1][kt], acc1);
    }

    // ---- fused projection for out[t-1] (h_t in LDS == hs[t-1]) on wave 0 ----
    if (w == 0 && t > 0) {
      f32x4 pacc = {bo, bo, bo, bo};
#pragma unroll
      for (int kt = 0; kt < 2; ++kt) {
        const bf16x8 phv = *(const bf16x8*)(ahi_base + 128 + kt * 64 + lg * 16);
        const bf16x8 plv = *(const bf16x8*)(alo_base + 128 + kt * 64 + lg * 16);
        pacc = MFMA16(phv, pbh[kt], pacc);
        pacc = MFMA16(phv, pbl[kt], pacc);
        pacc = MFMA16(plv, pbh[kt], pacc);
      }
      if (lane < 32) {
#pragma unroll
        for (int m = 0; m < 4; ++m) {
          const int row = lg * 4 + m;  // rows 0..7 real
          out[((size_t)(t - 1) * BB + r0 + row) * AA + lr] = pacc[m];
        }
      }
    }

    // ---- activation + gbuf scatter (real rows live in lanes 0..31) ----
    if (lane < 32) {
      const int q     = w >> 1;        // quadrant i,f,g,o
      const int jbase = (w & 1) * 32;
#pragma unroll
      for (int m = 0; m < 4; ++m) {
        float g0 = acc0[m], g1 = acc1[m];
        if (q == 2) { g0 = tanh_f(g0);    g1 = tanh_f(g1); }
        else        { g0 = sigmoid_f(g0); g1 = sigmoid_f(g1); }
        const int row = lg * 4 + m;
        s.gbuf[row][q][jbase + lr]      = g0;
        s.gbuf[row][q][jbase + 16 + lr] = g1;
      }
    }
    __syncthreads();

    // ---- elementwise c/h update: wave w handles row w, lane = hidden j ----
    {
      const float iv = s.gbuf[w][0][lane];
      const float fv = s.gbuf[w][1][lane];
      const float gv = s.gbuf[w][2][lane];
      const float ov = s.gbuf[w][3][lane];
      c_state = fv * c_state + iv * gv;
      const float h = ov * tanh_f(c_state);
      const short hh = f2bf(h);
      s.ahi[w][64 + lane] = (unsigned short)hh;
      s.alo[w][64 + lane] = (unsigned short)f2bf(h - bf2f(hh));
      if (t + 1 < TT) {
        const short xh = f2bf(xn);
        s.ahi[w][lane] = (unsigned short)xh;
        s.alo[w][lane] = (unsigned short)f2bf(xn - bf2f(xh));
      }
    }
    __syncthreads();
  }

  // ---- epilogue projection: out[TT-1] from final h ----
  if (w == 0) {
    f32x4 pacc = {bo, bo, bo, bo};
#pragma unroll
    for (int kt = 0; kt < 2; ++kt) {
      const bf16x8 phv = *(const bf16x8*)(ahi_base + 128 + kt * 64 + lg * 16);
      const bf16x8 plv = *(const bf16x8*)(alo_base + 128 + kt * 64 + lg * 16);
      pacc = MFMA16(phv, pbh[kt], pacc);
      pacc = MFMA16(phv, pbl[kt], pacc);
      pacc = MFMA16(plv, pbh[kt], pacc);
    }
    if (lane < 32) {
#pragma unroll
      for (int m = 0; m < 4; ++m) {
        const int row = lg * 4 + m;
        out[((size_t)(TT - 1) * BB + r0 + row) * AA + lr] = pacc[m];
      }
    }
  }
}

extern "C" void kernel_launch(void* const* d_in, const int* in_sizes, int n_in,
                              void* d_out, int out_size, void* d_ws, size_t ws_size,
                              hipStream_t stream) {
  const float* x     = (const float*)d_in[0];
  const float* W_ih  = (const float*)d_in[1];
  const float* W_hh  = (const float*)d_in[2];
  const float* b_ih  = (const float*)d_in[3];
  const float* b_hh  = (const float*)d_in[4];
  const float* W_out = (const float*)d_in[5];
  const float* b_out = (const float*)d_in[6];
  float* out = (float*)d_out;

  lstm_actor_mfma<<<dim3(BB / ROWS), dim3(512), 0, stream>>>(
      x, W_ih, W_hh, b_ih, b_hh, W_out, b_out, out);
}

// Round 3
// 469.101 us; speedup vs baseline: 10.1210x; 1.0584x over previous
//
#include <hip/hip_runtime.h>

// LSTM_Actor v3: T=512, B=2048, D=H=64, 4H=256, A=16.
// 256 blocks x 256 threads (4 waves), 8 batch rows/block, persistent over t.
// Key structure vs v2:
//  - hi/lo packed into M: A = [act_hi rows0-7 ; act_lo rows8-15]; 2 MFMA passes
//    (Bh, Bl) + shfl_xor(32) cross-half sum replaces 3 passes. fp32-level accuracy.
//  - j-partition: wave w owns hidden cols [16w,16w+16) for ALL 4 quadrants ->
//    elementwise fully in-register, gbuf gone, ONE barrier per step.
//  - act LDS double-buffered by t-parity (x and h), XOR-swizzled slots.
//  - x prefetched 2-3 steps ahead in regs; projection reuses gate A2/A3 frags.

#define TT 512
#define BB 2048
#define DD 64
#define HH 64
#define AA 16

typedef short bf16x8 __attribute__((ext_vector_type(8)));
typedef float f32x4 __attribute__((ext_vector_type(4)));

#define MFMA16(a, b, c) __builtin_amdgcn_mfma_f32_16x16x32_bf16((a), (b), (c), 0, 0, 0)

#if defined(__has_builtin)
#  if __has_builtin(__builtin_amdgcn_exp2f)
#    define EXP2F(x) __builtin_amdgcn_exp2f(x)
#  else
#    define EXP2F(x) exp2f(x)
#  endif
#  if __has_builtin(__builtin_amdgcn_rcpf)
#    define RCPF(x) __builtin_amdgcn_rcpf(x)
#  else
#    define RCPF(x) (1.0f/(x))
#  endif
#else
#  define EXP2F(x) exp2f(x)
#  define RCPF(x) (1.0f/(x))
#endif

__device__ __forceinline__ float sigmoid_f(float x) {
  return RCPF(1.0f + EXP2F(-1.4426950408889634f * x));
}
__device__ __forceinline__ float tanh_f(float x) {
  return 1.0f - 2.0f * RCPF(1.0f + EXP2F(2.8853900817779268f * x));
}
__device__ __forceinline__ short f2bf(float f) {  // RNE fp32->bf16
  union { float f; unsigned u; } v; v.f = f;
  unsigned r = v.u + 0x7FFFu + ((v.u >> 16) & 1u);
  return (short)(r >> 16);
}
__device__ __forceinline__ float bf2f(short s) {
  union { unsigned u; float f; } v; v.u = ((unsigned)(unsigned short)s) << 16;
  return v.f;
}
__device__ __forceinline__ unsigned pack2(short a, short b) {
  return (unsigned)(unsigned short)a | ((unsigned)(unsigned short)b << 16);
}

// act layout: 16 rows x 512B. Per row: [x_par0 0..127 | x_par1 128..255 |
// h_par0 256..383 | h_par1 384..511]. Rows 0-7 = hi bf16, rows 8-15 = lo bf16.
// 16B-slot XOR swizzle: slot' = slot_inner ^ (row & 7) within each 128B region.

__global__ __launch_bounds__(256, 1)
void lstm_actor_v3(const float* __restrict__ x,
                   const float* __restrict__ W_ih,
                   const float* __restrict__ W_hh,
                   const float* __restrict__ b_ih,
                   const float* __restrict__ b_hh,
                   const float* __restrict__ W_out,
                   const float* __restrict__ b_out,
                   float* __restrict__ out) {
  __shared__ __align__(16) unsigned short act[16 * 256];  // 8 KB
  char* actb = (char*)act;

  const int tid  = threadIdx.x;
  const int lane = tid & 63;
  const int w    = tid >> 6;       // wave 0..3: hidden slice j0 = 16w
  const int lr   = lane & 15;
  const int lg   = lane >> 4;
  const int half = lg >> 1;        // 0: activates m 0,1 ; 1: m 2,3
  const int lgp  = lg & 1;         // row group
  const int r0   = blockIdx.x * 8;
  const int j0   = w * 16;

  // ---- recurrent weight B-fragments (hi/lo), 4 quadrants x 4 k-tiles ----
  bf16x8 bh_[4][4], bl_[4][4];
#pragma unroll
  for (int q = 0; q < 4; ++q) {
    const int g = q * 64 + j0 + lr;
#pragma unroll
    for (int kt = 0; kt < 4; ++kt) {
      const int k0 = kt * 32 + lg * 8;
      const float* src = (kt < 2) ? (W_ih + g * 64 + k0) : (W_hh + g * 64 + (k0 - 64));
      bf16x8 vh, vl;
#pragma unroll
      for (int jj = 0; jj < 8; ++jj) {
        const float f = src[jj];
        const short hi = f2bf(f);
        vh[jj] = hi;
        vl[jj] = f2bf(f - bf2f(hi));
      }
      bh_[q][kt] = vh; bl_[q][kt] = vl;
    }
  }
  float bias[4];
#pragma unroll
  for (int q = 0; q < 4; ++q) bias[q] = b_ih[q * 64 + j0 + lr] + b_hh[q * 64 + j0 + lr];

  // ---- projection weights (wave 0) ----
  bf16x8 pbh[2], pbl[2];
  float bo = 0.0f;
  if (w == 0) {
    bo = b_out[lr];
#pragma unroll
    for (int kt = 0; kt < 2; ++kt) {
      const float* src = W_out + lr * 64 + kt * 32 + lg * 8;
      bf16x8 vh, vl;
#pragma unroll
      for (int jj = 0; jj < 8; ++jj) {
        const float f = src[jj];
        const short hi = f2bf(f);
        vh[jj] = hi;
        vl[jj] = f2bf(f - bf2f(hi));
      }
      pbh[kt] = vh; pbl[kt] = vl;
    }
  }

  // ---- zero LDS ----
  for (int i = tid; i < 16 * 256 / 2; i += 256) ((unsigned*)act)[i] = 0u;
  __syncthreads();

  // ---- per-lane A-fragment read addresses (t-invariant; +parity*128 in loop) ----
  int aoff[4];
#pragma unroll
  for (int kt = 0; kt < 4; ++kt) {
    const int inner  = (kt & 1) * 64 + lg * 16;       // byte within 128B region
    const int region = (kt < 2) ? 0 : 256;            // x vs h
    aoff[kt] = lr * 512 + region + (((inner >> 4) ^ (lr & 7)) << 4);
  }

  // ---- x staging geometry: lane covers (row = 2w + lane/32, j = 2*(lane&31)) ----
  const int xrow  = 2 * w + (lane >> 5);
  const int xj    = (lane & 31) * 2;
  const int xswz  = ((((lane & 31) >> 2) ^ (xrow & 7)) << 4) | ((4 * lane) & 15);
  const int xw_hi = xrow * 512 + xswz;
  const int xw_lo = (xrow + 8) * 512 + xswz;

  // ---- h write geometry: lane owns rows rA,rB at col j0+lr ----
  const int rA    = lgp * 4 + half * 2;
  const int rB    = rA + 1;
  const int hin   = 2 * (j0 + lr);
  const int hlow  = hin & 15;
  const int hslot = hin >> 4;
  const int hA_hi = rA * 512 + 256 + ((((hslot) ^ (rA & 7)) << 4) | hlow);
  const int hA_lo = (rA + 8) * 512 + 256 + ((((hslot) ^ (rA & 7)) << 4) | hlow);
  const int hB_hi = rB * 512 + 256 + ((((hslot) ^ (rB & 7)) << 4) | hlow);
  const int hB_lo = (rB + 8) * 512 + 256 + ((((hslot) ^ (rB & 7)) << 4) | hlow);

  // ---- stage x_0 into parity-0 x buffer ----
  {
    const float2 v = *(const float2*)(x + (size_t)(r0 + xrow) * DD + xj);
    const short h0 = f2bf(v.x), h1 = f2bf(v.y);
    *(unsigned*)(actb + xw_hi) = pack2(h0, h1);
    *(unsigned*)(actb + xw_lo) = pack2(f2bf(v.x - bf2f(h0)), f2bf(v.y - bf2f(h1)));
  }

  // ---- register prefetch of x_1, x_2 (2-3 step distance covers HBM latency) ----
  const float* xg0 = x + (size_t)(r0 + xrow) * DD + xj;
  float2 xw_reg = {0.f, 0.f}, xf_reg = {0.f, 0.f};
  xw_reg = *(const float2*)(xg0 + (size_t)1 * BB * DD);
  xf_reg = *(const float2*)(xg0 + (size_t)2 * BB * DD);
  const float* xg = xg0 + (size_t)3 * BB * DD;

  float c0 = 0.f, c1 = 0.f;
  __syncthreads();

  for (int t = 0; t < TT; ++t) {
    const int par  = (t & 1) * 128;
    const int parw = 128 - par;

    // ---- A-fragment reads (x_t | h_prev at parity par) ----
    const bf16x8 A0 = *(const bf16x8*)(actb + aoff[0] + par);
    const bf16x8 A1 = *(const bf16x8*)(actb + aoff[1] + par);
    const bf16x8 A2 = *(const bf16x8*)(actb + aoff[2] + par);
    const bf16x8 A3 = *(const bf16x8*)(actb + aoff[3] + par);

    // ---- write x_{t+1} into the OTHER parity buffer (no reader this step) ----
    if (t + 1 < TT) {
      const short h0 = f2bf(xw_reg.x), h1 = f2bf(xw_reg.y);
      *(unsigned*)(actb + xw_hi + parw) = pack2(h0, h1);
      *(unsigned*)(actb + xw_lo + parw) =
          pack2(f2bf(xw_reg.x - bf2f(h0)), f2bf(xw_reg.y - bf2f(h1)));
    }
    xw_reg = xf_reg;
    if (t + 3 < TT) xf_reg = *(const float2*)xg;
    xg += (size_t)BB * DD;

    // ---- gate GEMM: packed [Ah;Al] x (Bh then Bl), 32 MFMA ----
    f32x4 acc[4];
#pragma unroll
    for (int q = 0; q < 4; ++q) acc[q] = (f32x4){0.f, 0.f, 0.f, 0.f};
#pragma unroll
    for (int q = 0; q < 4; ++q) {
      acc[q] = MFMA16(A0, bh_[q][0], acc[q]);
      acc[q] = MFMA16(A1, bh_[q][1], acc[q]);
      acc[q] = MFMA16(A2, bh_[q][2], acc[q]);
      acc[q] = MFMA16(A3, bh_[q][3], acc[q]);
      acc[q] = MFMA16(A0, bl_[q][0], acc[q]);
      acc[q] = MFMA16(A1, bl_[q][1], acc[q]);
      acc[q] = MFMA16(A2, bl_[q][2], acc[q]);
      acc[q] = MFMA16(A3, bl_[q][3], acc[q]);
    }

    // ---- projection for out[t-1]: reuse A2/A3 (= h_prev = hs[t-1]) ----
    f32x4 pacc = {0.f, 0.f, 0.f, 0.f};
    if (w == 0 && t > 0) {
      pacc = MFMA16(A2, pbh[0], pacc);
      pacc = MFMA16(A3, pbh[1], pacc);
      pacc = MFMA16(A2, pbl[0], pacc);
      pacc = MFMA16(A3, pbl[1], pacc);
    }

    // ---- cross-half reduce (hi rows + lo rows), bias, m-split select ----
    float my0[4], my1[4];
#pragma unroll
    for (int q = 0; q < 4; ++q) {
      const float r0v = acc[q][0] + __shfl_xor(acc[q][0], 32, 64);
      const float r1v = acc[q][1] + __shfl_xor(acc[q][1], 32, 64);
      const float r2v = acc[q][2] + __shfl_xor(acc[q][2], 32, 64);
      const float r3v = acc[q][3] + __shfl_xor(acc[q][3], 32, 64);
      my0[q] = (half ? r2v : r0v) + bias[q];
      my1[q] = (half ? r3v : r1v) + bias[q];
    }

    // ---- in-register elementwise: lane owns (rA, j0+lr) and (rB, j0+lr) ----
    {
      const float iv = sigmoid_f(my0[0]), fv = sigmoid_f(my0[1]);
      const float gv = tanh_f(my0[2]),    ov = sigmoid_f(my0[3]);
      c0 = fv * c0 + iv * gv;
      const float h0 = ov * tanh_f(c0);
      const short hh0 = f2bf(h0);
      *(unsigned short*)(actb + hA_hi + parw) = (unsigned short)hh0;
      *(unsigned short*)(actb + hA_lo + parw) = (unsigned short)f2bf(h0 - bf2f(hh0));

      const float iv1 = sigmoid_f(my1[0]), fv1 = sigmoid_f(my1[1]);
      const float gv1 = tanh_f(my1[2]),    ov1 = sigmoid_f(my1[3]);
      c1 = fv1 * c1 + iv1 * gv1;
      const float h1 = ov1 * tanh_f(c1);
      const short hh1 = f2bf(h1);
      *(unsigned short*)(actb + hB_hi + parw) = (unsigned short)hh1;
      *(unsigned short*)(actb + hB_lo + parw) = (unsigned short)f2bf(h1 - bf2f(hh1));
    }

    // ---- projection reduce + out stores (wave 0) ----
    if (w == 0 && t > 0) {
      const float p0 = pacc[0] + __shfl_xor(pacc[0], 32, 64);
      const float p1 = pacc[1] + __shfl_xor(pacc[1], 32, 64);
      const float p2 = pacc[2] + __shfl_xor(pacc[2], 32, 64);
      const float p3 = pacc[3] + __shfl_xor(pacc[3], 32, 64);
      out[((size_t)(t - 1) * BB + r0 + rA) * AA + lr] = (half ? p2 : p0) + bo;
      out[((size_t)(t - 1) * BB + r0 + rB) * AA + lr] = (half ? p3 : p1) + bo;
    }

    __syncthreads();
  }

  // ---- epilogue: out[TT-1] from final h (parity TT&1 = 0) ----
  if (w == 0) {
    const int par = (TT & 1) * 128;
    const bf16x8 A2 = *(const bf16x8*)(actb + aoff[2] + par);
    const bf16x8 A3 = *(const bf16x8*)(actb + aoff[3] + par);
    f32x4 pacc = {0.f, 0.f, 0.f, 0.f};
    pacc = MFMA16(A2, pbh[0], pacc);
    pacc = MFMA16(A3, pbh[1], pacc);
    pacc = MFMA16(A2, pbl[0], pacc);
    pacc = MFMA16(A3, pbl[1], pacc);
    const float p0 = pacc[0] + __shfl_xor(pacc[0], 32, 64);
    const float p1 = pacc[1] + __shfl_xor(pacc[1], 32, 64);
    const float p2 = pacc[2] + __shfl_xor(pacc[2], 32, 64);
    const float p3 = pacc[3] + __shfl_xor(pacc[3], 32, 64);
    out[((size_t)(TT - 1) * BB + r0 + rA) * AA + lr] = (half ? p2 : p0) + bo;
    out[((size_t)(TT - 1) * BB + r0 + rB) * AA + lr] = (half ? p3 : p1) + bo;
  }
}

extern "C" void kernel_launch(void* const* d_in, const int* in_sizes, int n_in,
                              void* d_out, int out_size, void* d_ws, size_t ws_size,
                              hipStream_t stream) {
  const float* x     = (const float*)d_in[0];
  const float* W_ih  = (const float*)d_in[1];
  const float* W_hh  = (const float*)d_in[2];
  const float* b_ih  = (const float*)d_in[3];
  const float* b_hh  = (const float*)d_in[4];
  const float* W_out = (const float*)d_in[5];
  const float* b_out = (const float*)d_in[6];
  float* out = (float*)d_out;

  lstm_actor_v3<<<dim3(BB / 8), dim3(256), 0, stream>>>(
      x, W_ih, W_hh, b_ih, b_hh, W_out, b_out, out);
}

// Round 4
// 459.931 us; speedup vs baseline: 10.3228x; 1.0199x over previous
//
#include <hip/hip_runtime.h>

// LSTM_Actor v4: T=512, B=2048, D=H=64, 4H=256, A=16.
// 512 blocks x 256 threads (4 waves), 4 batch rows/block -> 2 blocks/CU
// co-resident (2 waves/SIMD) so independent blocks hide each other's latency.
// Interleaved M-packing: A-row 2r = hi(row r), 2r+1 = lo(row r) -> hi/lo
// partial sums land in adjacent C-regs of the same lane: in-register reduce,
// zero shuffles. One shfl_xor(32) per quadrant spreads rows to lg2/lg3 lanes
// so all 64 lanes run exactly one activation chain.
// One barrier per step; x/h LDS double-buffered by t-parity, XOR-swizzled.
// Projection round-robins across waves (w == t&3) to avoid a straggler wave.

#define TT 512
#define BB 2048
#define DD 64
#define HH 64
#define AA 16
#define RPB 4   // rows per block

typedef short bf16x8 __attribute__((ext_vector_type(8)));
typedef float f32x4 __attribute__((ext_vector_type(4)));

#define MFMA16(a, b, c) __builtin_amdgcn_mfma_f32_16x16x32_bf16((a), (b), (c), 0, 0, 0)

#if defined(__has_builtin)
#  if __has_builtin(__builtin_amdgcn_exp2f)
#    define EXP2F(x) __builtin_amdgcn_exp2f(x)
#  else
#    define EXP2F(x) exp2f(x)
#  endif
#  if __has_builtin(__builtin_amdgcn_rcpf)
#    define RCPF(x) __builtin_amdgcn_rcpf(x)
#  else
#    define RCPF(x) (1.0f/(x))
#  endif
#else
#  define EXP2F(x) exp2f(x)
#  define RCPF(x) (1.0f/(x))
#endif

__device__ __forceinline__ float sigmoid_f(float x) {
  return RCPF(1.0f + EXP2F(-1.4426950408889634f * x));
}
__device__ __forceinline__ float tanh_f(float x) {
  return 1.0f - 2.0f * RCPF(1.0f + EXP2F(2.8853900817779268f * x));
}
__device__ __forceinline__ short f2bf(float f) {  // RNE fp32->bf16
  union { float f; unsigned u; } v; v.f = f;
  unsigned r = v.u + 0x7FFFu + ((v.u >> 16) & 1u);
  return (short)(r >> 16);
}
__device__ __forceinline__ float bf2f(short s) {
  union { unsigned u; float f; } v; v.u = ((unsigned)(unsigned short)s) << 16;
  return v.f;
}
__device__ __forceinline__ unsigned pack2(short a, short b) {
  return (unsigned)(unsigned short)a | ((unsigned)(unsigned short)b << 16);
}

// act layout: 16 A-rows x 512 B. Per A-row: [x p0 0..127 | x p1 128..255 |
// h p0 256..383 | h p1 384..511]. A-row 2r = hi of block-row r, 2r+1 = lo.
// A-rows 8..15 stay zero. 16B-slot XOR swizzle within each 128B region:
// slot' = slot ^ (Arow & 7).

__global__ __launch_bounds__(256, 2)
void lstm_actor_v4(const float* __restrict__ x,
                   const float* __restrict__ W_ih,
                   const float* __restrict__ W_hh,
                   const float* __restrict__ b_ih,
                   const float* __restrict__ b_hh,
                   const float* __restrict__ W_out,
                   const float* __restrict__ b_out,
                   float* __restrict__ out) {
  __shared__ __align__(16) unsigned short act[16 * 256];  // 8 KB
  char* actb = (char*)act;

  const int tid  = threadIdx.x;
  const int lane = tid & 63;
  const int w    = tid >> 6;       // wave 0..3: hidden slice j0 = 16w; x-stage row w
  const int lr   = lane & 15;
  const int lg   = lane >> 4;
  const int r0   = blockIdx.x * RPB;
  const int j0   = w * 16;

  // ---- recurrent weight B-fragments (hi/lo), 4 quadrants x 4 k-tiles ----
  bf16x8 bh_[4][4], bl_[4][4];
#pragma unroll
  for (int q = 0; q < 4; ++q) {
    const int g = q * 64 + j0 + lr;
#pragma unroll
    for (int kt = 0; kt < 4; ++kt) {
      const int k0 = kt * 32 + lg * 8;
      const float* src = (kt < 2) ? (W_ih + g * 64 + k0) : (W_hh + g * 64 + (k0 - 64));
      bf16x8 vh, vl;
#pragma unroll
      for (int jj = 0; jj < 8; ++jj) {
        const float f = src[jj];
        const short hi = f2bf(f);
        vh[jj] = hi;
        vl[jj] = f2bf(f - bf2f(hi));
      }
      bh_[q][kt] = vh; bl_[q][kt] = vl;
    }
  }
  float bias[4];
#pragma unroll
  for (int q = 0; q < 4; ++q) bias[q] = b_ih[q * 64 + j0 + lr] + b_hh[q * 64 + j0 + lr];

  // ---- projection weights (ALL waves; projection round-robins over waves) ----
  bf16x8 pbh[2], pbl[2];
  const float bo = b_out[lr];
#pragma unroll
  for (int kt = 0; kt < 2; ++kt) {
    const float* src = W_out + lr * 64 + kt * 32 + lg * 8;
    bf16x8 vh, vl;
#pragma unroll
    for (int jj = 0; jj < 8; ++jj) {
      const float f = src[jj];
      const short hi = f2bf(f);
      vh[jj] = hi;
      vl[jj] = f2bf(f - bf2f(hi));
    }
    pbh[kt] = vh; pbl[kt] = vl;
  }

  // ---- zero LDS (A-rows 8-15 and all parities stay zero forever) ----
  for (int i = tid; i < 16 * 256 / 2; i += 256) ((unsigned*)act)[i] = 0u;

  // ---- per-lane A-fragment read offsets (add par in loop) ----
  int aoff[4];
#pragma unroll
  for (int kt = 0; kt < 4; ++kt) {
    const int inner  = (kt & 1) * 64 + lg * 16;   // byte within 128B region
    const int region = (kt < 2) ? 0 : 256;        // x vs h
    aoff[kt] = lr * 512 + region + ((((inner >> 4) ^ (lr & 7))) << 4);
  }

  // ---- x staging geometry: wave w stages block-row w, lane = j (1 fp32) ----
  const int xs   = lane >> 3;                     // slot 0..7
  const int xlow = (2 * lane) & 15;
  const int xw_hi = (2 * w) * 512     + (((xs ^ ((2 * w) & 7))) << 4)     + xlow;
  const int xw_lo = (2 * w + 1) * 512 + (((xs ^ ((2 * w + 1) & 7))) << 4) + xlow;

  // ---- h geometry: lane owns row hr = ((lg&1)<<1)|(lg>>1), col j0+lr ----
  const int hr    = ((lg & 1) << 1) | (lg >> 1);
  const int hbyte = 2 * (j0 + lr);
  const int hs    = hbyte >> 4, hlow = hbyte & 15;
  const int h_hi  = (2 * hr) * 512     + 256 + (((hs ^ ((2 * hr) & 7))) << 4)     + hlow;
  const int h_lo  = (2 * hr + 1) * 512 + 256 + (((hs ^ ((2 * hr + 1) & 7))) << 4) + hlow;

  __syncthreads();

  // ---- stage x_0 into parity-0, prefetch x_1, x_2 into registers ----
  const float* xg0 = x + (size_t)(r0 + w) * DD + lane;
  {
    const float x0 = *xg0;
    const short hh = f2bf(x0);
    *(unsigned short*)(actb + xw_hi) = (unsigned short)hh;
    *(unsigned short*)(actb + xw_lo) = (unsigned short)f2bf(x0 - bf2f(hh));
  }
  float xw_reg = xg0[(size_t)1 * BB * DD];
  float xf_reg = xg0[(size_t)2 * BB * DD];
  const float* xg = xg0 + (size_t)3 * BB * DD;

  float c_state = 0.0f;
  __syncthreads();

  for (int t = 0; t < TT; ++t) {
    const int par  = (t & 1) << 7;
    const int parw = 128 - par;

    // ---- A-fragment reads (x_t | h_{t-1} at parity par) ----
    const bf16x8 A0 = *(const bf16x8*)(actb + aoff[0] + par);
    const bf16x8 A1 = *(const bf16x8*)(actb + aoff[1] + par);
    const bf16x8 A2 = *(const bf16x8*)(actb + aoff[2] + par);
    const bf16x8 A3 = *(const bf16x8*)(actb + aoff[3] + par);

    // ---- stage x_{t+1} into other parity (no reader this step) ----
    if (t + 1 < TT) {
      const short hh = f2bf(xw_reg);
      *(unsigned short*)(actb + xw_hi + parw) = (unsigned short)hh;
      *(unsigned short*)(actb + xw_lo + parw) = (unsigned short)f2bf(xw_reg - bf2f(hh));
    }
    xw_reg = xf_reg;
    if (t + 3 < TT) xf_reg = *xg;
    xg += (size_t)BB * DD;

    // ---- gate GEMM: 32 MFMA (B hi then lo), hi/lo act packed in M ----
    f32x4 acc[4];
#pragma unroll
    for (int q = 0; q < 4; ++q) acc[q] = (f32x4){0.f, 0.f, 0.f, 0.f};
#pragma unroll
    for (int q = 0; q < 4; ++q) {
      acc[q] = MFMA16(A0, bh_[q][0], acc[q]);
      acc[q] = MFMA16(A1, bh_[q][1], acc[q]);
      acc[q] = MFMA16(A2, bh_[q][2], acc[q]);
      acc[q] = MFMA16(A3, bh_[q][3], acc[q]);
      acc[q] = MFMA16(A0, bl_[q][0], acc[q]);
      acc[q] = MFMA16(A1, bl_[q][1], acc[q]);
      acc[q] = MFMA16(A2, bl_[q][2], acc[q]);
      acc[q] = MFMA16(A3, bl_[q][3], acc[q]);
    }

    // ---- projection for out[t-1] on wave (t&3): reuse A2/A3 = hs[t-1] ----
    if (w == (t & 3) && t > 0) {
      f32x4 pacc = {0.f, 0.f, 0.f, 0.f};
      pacc = MFMA16(A2, pbh[0], pacc);
      pacc = MFMA16(A3, pbh[1], pacc);
      pacc = MFMA16(A2, pbl[0], pacc);
      pacc = MFMA16(A3, pbl[1], pacc);
      if (lg < 2) {  // lg0: out rows 0,1 ; lg1: rows 2,3 (interleaved hi/lo)
        const float o0 = pacc[0] + pacc[1] + bo;
        const float o1 = pacc[2] + pacc[3] + bo;
        const size_t base = ((size_t)(t - 1) * BB + r0 + 2 * lg) * AA + lr;
        out[base]      = o0;
        out[base + AA] = o1;
      }
    }

    // ---- in-register reduce + row redistribution (1 shfl per quadrant) ----
    // lg0: rows 0(a),1(b); lg1: rows 2(a),3(b); lg2/3 receive b via xor32.
    float sv[4];
#pragma unroll
    for (int q = 0; q < 4; ++q) {
      const float a0 = acc[q][0] + acc[q][1];
      const float b0 = acc[q][2] + acc[q][3];
      const float shipped = __shfl_xor(b0, 32, 64);
      sv[q] = ((lg < 2) ? a0 : shipped) + bias[q];
    }

    // ---- elementwise: every lane owns (row hr, col j0+lr) ----
    {
      const float iv = sigmoid_f(sv[0]);
      const float fv = sigmoid_f(sv[1]);
      const float gv = tanh_f(sv[2]);
      const float ov = sigmoid_f(sv[3]);
      c_state = fv * c_state + iv * gv;
      const float h = ov * tanh_f(c_state);
      const short hh = f2bf(h);
      *(unsigned short*)(actb + h_hi + parw) = (unsigned short)hh;
      *(unsigned short*)(actb + h_lo + parw) = (unsigned short)f2bf(h - bf2f(hh));
    }

    __syncthreads();
  }

  // ---- epilogue: out[TT-1] from final h (parity (TT&1)=0) ----
  if (w == (TT & 3)) {
    const int par = (TT & 1) << 7;
    const bf16x8 A2 = *(const bf16x8*)(actb + aoff[2] + par);
    const bf16x8 A3 = *(const bf16x8*)(actb + aoff[3] + par);
    f32x4 pacc = {0.f, 0.f, 0.f, 0.f};
    pacc = MFMA16(A2, pbh[0], pacc);
    pacc = MFMA16(A3, pbh[1], pacc);
    pacc = MFMA16(A2, pbl[0], pacc);
    pacc = MFMA16(A3, pbl[1], pacc);
    if (lg < 2) {
      const float o0 = pacc[0] + pacc[1] + bo;
      const float o1 = pacc[2] + pacc[3] + bo;
      const size_t base = ((size_t)(TT - 1) * BB + r0 + 2 * lg) * AA + lr;
      out[base]      = o0;
      out[base + AA] = o1;
    }
  }
}

extern "C" void kernel_launch(void* const* d_in, const int* in_sizes, int n_in,
                              void* d_out, int out_size, void* d_ws, size_t ws_size,
                              hipStream_t stream) {
  const float* x     = (const float*)d_in[0];
  const float* W_ih  = (const float*)d_in[1];
  const float* W_hh  = (const float*)d_in[2];
  const float* b_ih  = (const float*)d_in[3];
  const float* b_hh  = (const float*)d_in[4];
  const float* W_out = (const float*)d_in[5];
  const float* b_out = (const float*)d_in[6];
  float* out = (float*)d_out;

  lstm_actor_v4<<<dim3(BB / RPB), dim3(256), 0, stream>>>(
      x, W_ih, W_hh, b_ih, b_hh, W_out, b_out, out);
}

// Round 5
// 345.072 us; speedup vs baseline: 13.7588x; 1.3329x over previous
//
#include <hip/hip_runtime.h>

// LSTM_Actor v5: T=512, B=2048, D=H=64, 4H=256, A=16.
// 256 blocks x 512 threads (8 waves), 8 rows/block -> 8 waves/CU (2/SIMD).
// All 16 MFMA A-rows real: A-row 2r = hi(row r), 2r+1 = lo(row r).
// Wave w owns j-slice [8w, 8w+8) for ALL quadrants, packed as 2 N-tiles:
//   tile0 cols = {i,f} x 8 j's, tile1 cols = {g,o} x 8 j's
// -> 16 gate MFMA/wave/step (4 indep chains of 4); chip-wide 32768 MFMA/step
//    (v3's minimum) at v4's occupancy.
// One shfl_xor(8) pair completes per-lane (row,j) i,f,g,o -> all 64 lanes do
// exactly one activation chain. One barrier/step; x/h double-buffered by
// t-parity, XOR-swizzled slots. Projection round-robins waves (w == t&7).

#define TT 512
#define BB 2048
#define DD 64
#define HH 64
#define AA 16

typedef short bf16x8 __attribute__((ext_vector_type(8)));
typedef float f32x4 __attribute__((ext_vector_type(4)));

#define MFMA16(a, b, c) __builtin_amdgcn_mfma_f32_16x16x32_bf16((a), (b), (c), 0, 0, 0)

#if defined(__has_builtin)
#  if __has_builtin(__builtin_amdgcn_exp2f)
#    define EXP2F(x) __builtin_amdgcn_exp2f(x)
#  else
#    define EXP2F(x) exp2f(x)
#  endif
#  if __has_builtin(__builtin_amdgcn_rcpf)
#    define RCPF(x) __builtin_amdgcn_rcpf(x)
#  else
#    define RCPF(x) (1.0f/(x))
#  endif
#else
#  define EXP2F(x) exp2f(x)
#  define RCPF(x) (1.0f/(x))
#endif

__device__ __forceinline__ float sigmoid_f(float x) {
  return RCPF(1.0f + EXP2F(-1.4426950408889634f * x));
}
__device__ __forceinline__ float tanh_f(float x) {
  return 1.0f - 2.0f * RCPF(1.0f + EXP2F(2.8853900817779268f * x));
}
__device__ __forceinline__ short f2bf(float f) {  // RNE fp32->bf16
  union { float f; unsigned u; } v; v.f = f;
  unsigned r = v.u + 0x7FFFu + ((v.u >> 16) & 1u);
  return (short)(r >> 16);
}
__device__ __forceinline__ float bf2f(short s) {
  union { unsigned u; float f; } v; v.u = ((unsigned)(unsigned short)s) << 16;
  return v.f;
}

// act layout: 16 A-rows x 512 B. Per A-row: [x p0 0..127 | x p1 128..255 |
// h p0 256..383 | h p1 384..511]. A-row 2r = hi of real row r, 2r+1 = lo.
// 16B-slot XOR swizzle within each 128B region: slot' = slot ^ (Arow & 7).

__global__ __launch_bounds__(512, 2)
void lstm_actor_v5(const float* __restrict__ x,
                   const float* __restrict__ W_ih,
                   const float* __restrict__ W_hh,
                   const float* __restrict__ b_ih,
                   const float* __restrict__ b_hh,
                   const float* __restrict__ W_out,
                   const float* __restrict__ b_out,
                   float* __restrict__ out) {
  __shared__ __align__(16) unsigned short act[16 * 256];  // 8 KB
  char* actb = (char*)act;

  const int tid  = threadIdx.x;
  const int lane = tid & 63;
  const int w    = tid >> 6;       // wave 0..7: j-slice j0 = 8w; x-stage row w
  const int lr   = lane & 15;
  const int lg   = lane >> 4;
  const int r0   = blockIdx.x * 8;
  const int j0   = w * 8;
  const int qq   = lr >> 3;        // 0/1: which quadrant within the tile pair
  const int jj   = lr & 7;         // j within slice

  // ---- recurrent weight B-fragments (hi/lo), 2 packed N-tiles x 4 k-tiles ----
  // tile nt cols: gate = (nt*2 + qq)*64 + j0 + jj  (nt0:{i,f}, nt1:{g,o})
  bf16x8 bh_[2][4], bl_[2][4];
  float bias[2];
#pragma unroll
  for (int nt = 0; nt < 2; ++nt) {
    const int g = (nt * 2 + qq) * 64 + j0 + jj;
    bias[nt] = b_ih[g] + b_hh[g];
#pragma unroll
    for (int kt = 0; kt < 4; ++kt) {
      const int k0 = kt * 32 + lg * 8;
      const float* src = (kt < 2) ? (W_ih + g * 64 + k0) : (W_hh + g * 64 + (k0 - 64));
      bf16x8 vh, vl;
#pragma unroll
      for (int u = 0; u < 8; ++u) {
        const float f = src[u];
        const short hi = f2bf(f);
        vh[u] = hi;
        vl[u] = f2bf(f - bf2f(hi));
      }
      bh_[nt][kt] = vh; bl_[nt][kt] = vl;
    }
  }

  // ---- projection weights (all waves; round-robin use) ----
  bf16x8 pbh[2], pbl[2];
  const float bo = b_out[lr];
#pragma unroll
  for (int kt = 0; kt < 2; ++kt) {
    const float* src = W_out + lr * 64 + kt * 32 + lg * 8;
    bf16x8 vh, vl;
#pragma unroll
    for (int u = 0; u < 8; ++u) {
      const float f = src[u];
      const short hi = f2bf(f);
      vh[u] = hi;
      vl[u] = f2bf(f - bf2f(hi));
    }
    pbh[kt] = vh; pbl[kt] = vl;
  }

  // ---- zero LDS (also zero-inits h) ----
  for (int i = tid; i < 16 * 256 / 2; i += 512) ((unsigned*)act)[i] = 0u;

  // ---- per-lane A-fragment read offsets (add par in loop) ----
  int aoff[4];
#pragma unroll
  for (int kt = 0; kt < 4; ++kt) {
    const int inner  = (kt & 1) * 64 + lg * 16;   // byte within 128B region
    const int region = (kt < 2) ? 0 : 256;        // x vs h
    aoff[kt] = lr * 512 + region + ((((inner >> 4) ^ (lr & 7))) << 4);
  }

  // ---- x staging: wave w stages real row w, lane = j (1 fp32/lane) ----
  const int xs    = lane >> 3;
  const int xlow  = (2 * lane) & 15;
  const int xw_hi = (2 * w) * 512     + (((xs ^ ((2 * w) & 7))) << 4)     + xlow;
  const int xw_lo = (2 * w + 1) * 512 + (((xs ^ ((2 * w + 1) & 7))) << 4) + xlow;

  // ---- h write geometry: lane owns (row hrow, col hj) ----
  const int hrow  = 2 * lg + qq;            // real row 0..7 (qq selects pair elt)
  const int hj    = j0 + jj;
  const int hbyte = 2 * hj;
  const int hs    = hbyte >> 4, hlow = hbyte & 15;
  const int h_hi  = (2 * hrow) * 512     + 256 + (((hs ^ ((2 * hrow) & 7))) << 4)     + hlow;
  const int h_lo  = (2 * hrow + 1) * 512 + 256 + (((hs ^ ((2 * hrow + 1) & 7))) << 4) + hlow;

  __syncthreads();

  // ---- stage x_0 (parity 0), prefetch x_1, x_2 ----
  const float* xg0 = x + (size_t)(r0 + w) * DD + lane;
  {
    const float x0 = *xg0;
    const short hh = f2bf(x0);
    *(unsigned short*)(actb + xw_hi) = (unsigned short)hh;
    *(unsigned short*)(actb + xw_lo) = (unsigned short)f2bf(x0 - bf2f(hh));
  }
  float xw_reg = xg0[(size_t)1 * BB * DD];
  float xf_reg = xg0[(size_t)2 * BB * DD];
  const float* xg = xg0 + (size_t)3 * BB * DD;

  float c_state = 0.0f;
  __syncthreads();

  for (int t = 0; t < TT; ++t) {
    const int par  = (t & 1) << 7;
    const int parw = 128 - par;

    // ---- A-fragment reads (x_t | h_{t-1} at parity par) ----
    const bf16x8 A0 = *(const bf16x8*)(actb + aoff[0] + par);
    const bf16x8 A1 = *(const bf16x8*)(actb + aoff[1] + par);
    const bf16x8 A2 = *(const bf16x8*)(actb + aoff[2] + par);
    const bf16x8 A3 = *(const bf16x8*)(actb + aoff[3] + par);

    // ---- stage x_{t+1} into other parity ----
    if (t + 1 < TT) {
      const short hh = f2bf(xw_reg);
      *(unsigned short*)(actb + xw_hi + parw) = (unsigned short)hh;
      *(unsigned short*)(actb + xw_lo + parw) = (unsigned short)f2bf(xw_reg - bf2f(hh));
    }
    xw_reg = xf_reg;
    if (t + 3 < TT) xf_reg = *xg;
    xg += (size_t)BB * DD;

    // ---- gate GEMM: 16 MFMA as 4 independent chains of 4 ----
    f32x4 aH0 = {0.f,0.f,0.f,0.f}, aL0 = {0.f,0.f,0.f,0.f};
    f32x4 aH1 = {0.f,0.f,0.f,0.f}, aL1 = {0.f,0.f,0.f,0.f};
    aH0 = MFMA16(A0, bh_[0][0], aH0);  aH1 = MFMA16(A0, bh_[1][0], aH1);
    aL0 = MFMA16(A0, bl_[0][0], aL0);  aL1 = MFMA16(A0, bl_[1][0], aL1);
    aH0 = MFMA16(A1, bh_[0][1], aH0);  aH1 = MFMA16(A1, bh_[1][1], aH1);
    aL0 = MFMA16(A1, bl_[0][1], aL0);  aL1 = MFMA16(A1, bl_[1][1], aL1);
    aH0 = MFMA16(A2, bh_[0][2], aH0);  aH1 = MFMA16(A2, bh_[1][2], aH1);
    aL0 = MFMA16(A2, bl_[0][2], aL0);  aL1 = MFMA16(A2, bl_[1][2], aL1);
    aH0 = MFMA16(A3, bh_[0][3], aH0);  aH1 = MFMA16(A3, bh_[1][3], aH1);
    aL0 = MFMA16(A3, bl_[0][3], aL0);  aL1 = MFMA16(A3, bl_[1][3], aL1);

    // ---- projection for out[t-1] on wave (t&7): A2/A3 = hs[t-1] ----
    f32x4 pacc = {0.f,0.f,0.f,0.f};
    const bool do_proj = (w == (t & 7)) && (t > 0);
    if (do_proj) {
      pacc = MFMA16(A2, pbh[0], pacc);
      pacc = MFMA16(A3, pbh[1], pacc);
      pacc = MFMA16(A2, pbl[0], pacc);
      pacc = MFMA16(A3, pbl[1], pacc);
    }

    // ---- reduce hi/lo (adjacent C rows) + bias; 1 shfl pair redistributes ----
    const f32x4 t0 = aH0 + aL0;
    const f32x4 t1 = aH1 + aL1;
    const float a_val0 = t0[0] + t0[1] + bias[0];  // row 2lg,  tile0 (i or f)
    const float b_val0 = t0[2] + t0[3] + bias[0];  // row 2lg+1,tile0
    const float a_val1 = t1[0] + t1[1] + bias[1];  // row 2lg,  tile1 (g or o)
    const float b_val1 = t1[2] + t1[3] + bias[1];  // row 2lg+1,tile1
    const float ship0 = qq ? a_val0 : b_val0;
    const float ship1 = qq ? a_val1 : b_val1;
    const float rcv0 = __shfl_xor(ship0, 8, 64);
    const float rcv1 = __shfl_xor(ship1, 8, 64);
    // lane qq=0 -> row 2lg:   i=a_val0, g=a_val1, f=rcv0, o=rcv1
    // lane qq=1 -> row 2lg+1: f=b_val0, o=b_val1, i=rcv0, g=rcv1
    const float iv_ = qq ? rcv0 : a_val0;
    const float fv_ = qq ? b_val0 : rcv0;
    const float gv_ = qq ? rcv1 : a_val1;
    const float ov_ = qq ? b_val1 : rcv1;

    // ---- elementwise: lane owns (hrow, hj) ----
    {
      const float iv = sigmoid_f(iv_);
      const float fv = sigmoid_f(fv_);
      const float gv = tanh_f(gv_);
      const float ov = sigmoid_f(ov_);
      c_state = fv * c_state + iv * gv;
      const float h = ov * tanh_f(c_state);
      const short hh = f2bf(h);
      *(unsigned short*)(actb + h_hi + parw) = (unsigned short)hh;
      *(unsigned short*)(actb + h_lo + parw) = (unsigned short)f2bf(h - bf2f(hh));
    }

    // ---- projection reduce + stores (rows 2lg, 2lg+1; col lr) ----
    if (do_proj) {
      const float oA = pacc[0] + pacc[1] + bo;
      const float oB = pacc[2] + pacc[3] + bo;
      const size_t base = ((size_t)(t - 1) * BB + r0 + 2 * lg) * AA + lr;
      out[base]      = oA;
      out[base + AA] = oB;
    }

    __syncthreads();
  }

  // ---- epilogue: out[TT-1] from final h (parity (TT&1)=0) ----
  if (w == (TT & 7)) {
    const int par = (TT & 1) << 7;
    const bf16x8 A2 = *(const bf16x8*)(actb + aoff[2] + par);
    const bf16x8 A3 = *(const bf16x8*)(actb + aoff[3] + par);
    f32x4 pacc = {0.f,0.f,0.f,0.f};
    pacc = MFMA16(A2, pbh[0], pacc);
    pacc = MFMA16(A3, pbh[1], pacc);
    pacc = MFMA16(A2, pbl[0], pacc);
    pacc = MFMA16(A3, pbl[1], pacc);
    const float oA = pacc[0] + pacc[1] + bo;
    const float oB = pacc[2] + pacc[3] + bo;
    const size_t base = ((size_t)(TT - 1) * BB + r0 + 2 * lg) * AA + lr;
    out[base]      = oA;
    out[base + AA] = oB;
  }
}

extern "C" void kernel_launch(void* const* d_in, const int* in_sizes, int n_in,
                              void* d_out, int out_size, void* d_ws, size_t ws_size,
                              hipStream_t stream) {
  const float* x     = (const float*)d_in[0];
  const float* W_ih  = (const float*)d_in[1];
  const float* W_hh  = (const float*)d_in[2];
  const float* b_ih  = (const float*)d_in[3];
  const float* b_hh  = (const float*)d_in[4];
  const float* W_out = (const float*)d_in[5];
  const float* b_out = (const float*)d_in[6];
  float* out = (float*)d_out;

  lstm_actor_v5<<<dim3(BB / 8), dim3(512), 0, stream>>>(
      x, W_ih, W_hh, b_ih, b_hh, W_out, b_out, out);
}